// Round 13
// baseline (2713.138 us; speedup 1.0000x reference)
//
#include <hip/hip_runtime.h>

#define B_SZ 2048
#define HID  1024
#define G4   4096
#define IN_D 512
#define T_LEN 20
#define NT   (HID/32)
#define NBLK 512

// Tile swizzle: 16B chunk q of row r stored at q ^ ((r>>1)&3) -> b128 frag
// reads land 8 banks x 2-way (free, m136); DMA writes stay linear.
#define POFF(r, q) ((r)*32 + ((((q) ^ (((r) >> 1) & 3))) << 3))

typedef __attribute__((ext_vector_type(8))) _Float16 f16x8;
typedef __attribute__((ext_vector_type(4))) float f32x4;
typedef const __attribute__((address_space(1))) void* gas_p;
typedef __attribute__((address_space(3))) void* las_p;

__device__ __forceinline__ float bf2f(ushort u){
  union { unsigned int i; float f; } v; v.i = ((unsigned int)u) << 16; return v.f;
}
__device__ __forceinline__ ushort f2bf(float f){
  union { float f; unsigned int i; } v; v.f = f;
  unsigned int r = v.i + 0x7fffu + ((v.i >> 16) & 1u);
  return (ushort)(r >> 16);
}
// fp16 RTN. All tensor magnitudes here (|h|<=1, |W|~0.03, |c0|~N(0,1)) are far
// inside fp16 range; rel err 2^-11 beats bf16's 2^-9.
__device__ __forceinline__ ushort f2h(float f){
  _Float16 h = (_Float16)f;
  union { _Float16 h; ushort u; } v; v.h = h; return v.u;
}
__device__ __forceinline__ float rdv(const void* p, long idx, int fl){
  return fl ? ((const float*)p)[idx] : bf2f(((const ushort*)p)[idx]);
}
__device__ __forceinline__ float sigm(float x){ return 1.0f/(1.0f + __expf(-x)); }
__device__ __forceinline__ float tanh_f(float x){
  float e = __expf(2.0f*x);
  return 1.0f - 2.0f/(e + 1.0f);
}

// flag=1 -> fp32 inputs; flag=0 -> bf16. Also zeroes the grid-barrier counter
// (workspace is not guaranteed zeroed; re-zeroed on every launch/replay).
__global__ void detect_dtype(const ushort* __restrict__ h0bits, int* __restrict__ flag,
                             int* __restrict__ bar){
  int weird = 0;
  for (int i = 0; i < 256; i += 2){
    float a = fabsf(bf2f(h0bits[i]));
    if (!(a >= 1e-8f && a <= 1e4f)) weird++;
  }
  *flag = (weird >= 32) ? 1 : 0;
  *bar = 0;
}

// Packed+swizzled fp16 layouts (every wave-level access = dense span):
//   h: tile (mb*32+kt) of 4096 halfs, element (b&127, j&31) at POFF
//   W: tile (nb*32+kt) of 4096 halfs, row r = g*32+(j&31)
__global__ void canon(const void* __restrict__ h0, const void* __restrict__ c0,
                      const void* __restrict__ whh, const int* __restrict__ flag,
                      ushort* __restrict__ hA,
                      float* __restrict__ c_state,
                      ushort* __restrict__ wpk){
  const int fl = *flag;
  long i = (long)blockIdx.x * 256 + threadIdx.x;
  const long N1 = (long)B_SZ * HID;
  const long N3 = (long)G4 * HID;
  if (i < N1){
    const int b = (int)(i >> 10), j = (int)(i & 1023);
    const int r = b & 127, q = (j >> 3) & 3;
    const long po = ((long)(b >> 7)*32 + (j >> 5))*4096 + POFF(r, q) + (j & 7);
    hA[po] = f2h(rdv(h0, i, fl));
    return;
  }
  i -= N1;
  if (i < N1){ c_state[i] = rdv(c0, i, fl); return; }
  i -= N1;
  if (i < N3){
    const int n = (int)(i >> 10), k = (int)(i & 1023);
    const int g = n >> 10, j = n & 1023;
    const int nb = j >> 5, r = g*32 + (j & 31);
    const int kt = k >> 5, q = (k >> 3) & 3;
    const long base = ((long)(nb*32 + kt))*4096 + POFF(r, q) + (k & 7);
    wpk[base] = f2h(rdv(whh, i, fl));
  }
}

// Fold embedding + input GEMM + biases into exact rank-2 update:
// gates_x[t,b,n] = obs[t,b,0]*M0[n] + obs[t,b,1]*M1[n] + Beff[n]
__global__ void fold_emb(const void* __restrict__ Wih, const void* __restrict__ Wemb,
                         const void* __restrict__ bemb, const void* __restrict__ bih,
                         const void* __restrict__ bhh, const int* __restrict__ flag,
                         float* __restrict__ M0, float* __restrict__ M1, float* __restrict__ Beff){
  const int n = blockIdx.x;
  const int lane = threadIdx.x;
  const int fl = *flag;
  float s0 = 0.f, s1 = 0.f, sb = 0.f;
  for (int j = lane; j < IN_D; j += 64){
    float w  = rdv(Wih, (long)n*IN_D + j, fl);
    float e0 = rdv(Wemb, 2L*j, fl);
    float e1 = rdv(Wemb, 2L*j + 1, fl);
    float be = rdv(bemb, j, fl);
    s0 += w*e0; s1 += w*e1; sb += w*be;
  }
  #pragma unroll
  for (int off = 32; off > 0; off >>= 1){
    s0 += __shfl_down(s0, off, 64);
    s1 += __shfl_down(s1, off, 64);
    sb += __shfl_down(sb, off, 64);
  }
  if (lane == 0){
    M0[n] = s0; M1[n] = s1;
    Beff[n] = sb + rdv(bih, n, fl) + rdv(bhh, n, fl);
  }
}

// Device-scope grid barrier (Guideline 16): release fence from every thread
// (drains vmcnt + L2 writeback), block rendezvous, one atomicAdd per block on
// a monotonic counter, acquire spin, acquire fence (invalidate). Safe because
// all NBLK blocks are co-resident by construction (512 = 256 CU x 2; LDS 48KB
// and launch_bounds(256,2) guarantee 2 blocks/CU).
__device__ __forceinline__ void grid_barrier(int* __restrict__ bar, int target){
  __threadfence();
  __syncthreads();
  if (threadIdx.x == 0){
    atomicAdd(bar, 1);
    while (__hip_atomic_load(bar, __ATOMIC_ACQUIRE, __HIP_MEMORY_SCOPE_AGENT) < target)
      __builtin_amdgcn_s_sleep(8);
  }
  __syncthreads();
  __threadfence();
}

// Persistent fused 20-step LSTM. Inner K-loop = R11's proven 3-ring counted
// vmcnt schedule (never a full drain mid-loop), geometry = 256thr/4 waves,
// wave tile 64x64. Fusion removes per-step fixed costs: 20 launch gaps,
// per-step prologue L2 fill, offset/bias reload, and ALL c_state traffic --
// c lives in 16 VGPRs for the whole sequence. h ping-pongs between two packed
// buffers with a grid barrier + device fences between steps (cross-XCD h
// visibility). vmcnt counting is sound: the barrier's release fence drains
// all epilogue stores/loads, so each step's prologue starts at vmcnt=0.
__global__ __launch_bounds__(256, 2)
void lstm_persist(ushort* __restrict__ hA, ushort* __restrict__ hB,
                  void* __restrict__ out_final,
                  const float* __restrict__ c_init,
                  const ushort* __restrict__ wpk,
                  const float* __restrict__ M0, const float* __restrict__ M1,
                  const float* __restrict__ Beff,
                  const void* __restrict__ obs_raw,
                  const int* __restrict__ flag, int* __restrict__ bar)
{
  // 3-ring x [A 4096 | B 4096] halfs = 48 KB
  __shared__ __align__(16) ushort lds[3*8192];

  const int tid  = threadIdx.x;
  const int wave = tid >> 6;
  const int lane = tid & 63;
  const int l15  = lane & 15;
  const int quad = lane >> 4;
  const int wm   = wave & 1;    // M half (64 rows)
  const int wn   = wave >> 1;   // j half (16 cols of each gate)

  // XCD partition: xcd x owns mb in {(x&1)*8 + 0..7}, nb in {(x>>1)*8 + 0..7}
  const int bid = blockIdx.x;
  const int xcd = bid & 7, u = bid >> 3;
  const int mb  = ((xcd & 1) << 3) | (u & 7);       // 0..15
  const int nb  = ((xcd >> 1) << 3) | (u >> 3);     // 0..31
  const int n0  = nb << 5;

  const ushort* wB = wpk + (size_t)nb*32*4096;
  const int dOff = tid*8;   // halfs; 256 thr x 16B = 2048 halfs per instr

  #define DMA_TILE(aBp, kt, buf) do {                                         \
    const ushort* s0 = (aBp) + (size_t)(kt)*4096;                             \
    const ushort* s1 = wB + (size_t)(kt)*4096;                                \
    ushort* d = &lds[(buf)*8192];                                             \
    __builtin_amdgcn_global_load_lds((gas_p)(s0+dOff),      (las_p)(d+dOff),      16,0,0); \
    __builtin_amdgcn_global_load_lds((gas_p)(s0+2048+dOff), (las_p)(d+2048+dOff), 16,0,0); \
    __builtin_amdgcn_global_load_lds((gas_p)(s1+dOff),      (las_p)(d+4096+dOff), 16,0,0); \
    __builtin_amdgcn_global_load_lds((gas_p)(s1+2048+dOff), (las_p)(d+6144+dOff), 16,0,0); \
  } while (0)

  // kt-invariant swizzled frag-read offsets (halfs), computed once.
  int offA[4], offB[4];
  #pragma unroll
  for (int mt = 0; mt < 4; mt++) {
    const int r = wm*64 + mt*16 + l15;
    offA[mt] = POFF(r, quad);
  }
  #pragma unroll
  for (int g = 0; g < 4; g++) {
    const int r = g*32 + wn*16 + l15;
    offB[g] = 4096 + POFF(r, quad);
  }

  // Once-per-sequence loads: biases, rank-2 folds, and the c-state (16 VGPRs,
  // never touches memory again until done).
  const int fl = *flag;
  const int j = n0 + wn*16 + l15;
  float bi[4], m0v[4], m1v[4];
  #pragma unroll
  for (int g = 0; g < 4; g++) {
    bi[g]  = Beff[g*HID + j];
    m0v[g] = M0[g*HID + j];
    m1v[g] = M1[g*HID + j];
  }
  float creg[4][4];
  #pragma unroll
  for (int mt = 0; mt < 4; mt++)
    #pragma unroll
    for (int r = 0; r < 4; r++) {
      const int b = mb*128 + wm*64 + mt*16 + quad*4 + r;
      creg[mt][r] = c_init[(size_t)b*HID + j];
    }
  const int jq = (j >> 3) & 3;   // k-chunk of col j in packed h layout

  #pragma unroll 1
  for (int t = 0; t < T_LEN; t++) {
    const ushort* hin = (t & 1) ? hB : hA;
    ushort*       hout = (t & 1) ? hA : hB;
    const ushort* aB = hin + (size_t)mb*32*4096;

    f32x4 acc[4][4];
    #pragma unroll
    for (int g = 0; g < 4; g++)
      #pragma unroll
      for (int mt = 0; mt < 4; mt++)
        acc[g][mt] = (f32x4){0.f, 0.f, 0.f, 0.f};

    // Prologue: stage tiles 0,1; wait only tile 0's 4 loads.
    DMA_TILE(aB, 0, 0);
    DMA_TILE(aB, 1, 1);
    asm volatile("s_waitcnt vmcnt(4)" ::: "memory");
    asm volatile("s_barrier" ::: "memory");

    int cur = 0;
    #pragma unroll 1
    for (int kt = 0; kt < NT; kt++) {
      const int sb = cur * 8192;

      f16x8 a[4], b[4];
      #pragma unroll
      for (int mt = 0; mt < 4; mt++)
        a[mt] = *reinterpret_cast<const f16x8*>(&lds[sb + offA[mt]]);
      #pragma unroll
      for (int g = 0; g < 4; g++)
        b[g] = *reinterpret_cast<const f16x8*>(&lds[sb + offB[g]]);

      if (kt + 2 < NT) {
        int stg = cur + 2; if (stg >= 3) stg -= 3;
        DMA_TILE(aB, kt + 2, stg);
      }

      #pragma unroll
      for (int g = 0; g < 4; g++)
        #pragma unroll
        for (int mt = 0; mt < 4; mt++)
          acc[g][mt] = __builtin_amdgcn_mfma_f32_16x16x32_f16(a[mt], b[g], acc[g][mt], 0, 0, 0);

      if (kt + 2 < NT) asm volatile("s_waitcnt vmcnt(4)" ::: "memory");
      else             asm volatile("s_waitcnt vmcnt(0)" ::: "memory");
      asm volatile("s_barrier" ::: "memory");
      __builtin_amdgcn_sched_barrier(0);

      cur = (cur == 2) ? 0 : cur + 1;
    }

    // Epilogue: fused LSTM cell, c in registers.
    #pragma unroll
    for (int mt = 0; mt < 4; mt++) {
      #pragma unroll
      for (int r = 0; r < 4; r++) {
        const int bl7 = wm*64 + mt*16 + quad*4 + r;   // b & 127
        const int b   = mb*128 + bl7;
        const long oidx = ((long)t * B_SZ + b) * 2;
        const float o0 = rdv(obs_raw, oidx, fl);
        const float o1 = rdv(obs_raw, oidx + 1, fl);
        float pi = acc[0][mt][r] + o0*m0v[0] + o1*m1v[0] + bi[0];
        float pf = acc[1][mt][r] + o0*m0v[1] + o1*m1v[1] + bi[1];
        float pg = acc[2][mt][r] + o0*m0v[2] + o1*m1v[2] + bi[2];
        float po = acc[3][mt][r] + o0*m0v[3] + o1*m1v[3] + bi[3];
        float cn = sigm(pf)*creg[mt][r] + sigm(pi)*tanh_f(pg);
        float hn = sigm(po)*tanh_f(cn);
        creg[mt][r] = cn;
        if (t == T_LEN - 1) {
          const size_t off = (size_t)b*HID + j;
          if (fl) ((float*)out_final)[off] = hn;
          else    ((ushort*)out_final)[off] = f2bf(hn);
        } else {
          const long hpo = ((long)mb*32 + (j >> 5))*4096 + POFF(bl7, jq) + (j & 7);
          hout[hpo] = f2h(hn);
        }
      }
    }

    // Device-scope step separator (drains stores; makes h visible cross-XCD).
    if (t < T_LEN - 1) grid_barrier(bar, NBLK * (t + 1));
  }
  #undef DMA_TILE
}

extern "C" void kernel_launch(void* const* d_in, const int* in_sizes, int n_in,
                              void* d_out, int out_size, void* d_ws, size_t ws_size,
                              hipStream_t stream) {
  const void* obs  = d_in[0];
  const void* h0   = d_in[1];
  const void* c0   = d_in[2];
  const void* Wemb = d_in[3];
  const void* bemb = d_in[4];
  const void* Wih  = d_in[5];
  const void* Whh  = d_in[6];
  const void* bih  = d_in[7];
  const void* bhh  = d_in[8];

  char* w = (char*)d_ws;
  int*    flag    = (int*)w;
  int*    bar     = (int*)(w + 128);
  float*  M0      = (float*)(w + 256);
  float*  M1      = M0 + G4;
  float*  Beff    = M1 + G4;
  float*  c_state = Beff + G4;                              // 8 MB
  ushort* wpk     = (ushort*)(c_state + (size_t)B_SZ*HID);  // 8 MB packed W (fp16)
  ushort* hA      = wpk + (size_t)G4*HID;                   // 4 MB
  ushort* hB      = hA + (size_t)B_SZ*HID;                  // 4 MB  (~24 MB total)

  detect_dtype<<<1, 1, 0, stream>>>((const ushort*)h0, flag, bar);

  long totalCanon = 2L*B_SZ*HID + (long)G4*HID;
  canon<<<(int)((totalCanon + 255)/256), 256, 0, stream>>>(
      h0, c0, Whh, flag, hA, c_state, wpk);

  fold_emb<<<G4, 64, 0, stream>>>(Wih, Wemb, bemb, bih, bhh, flag, M0, M1, Beff);

  lstm_persist<<<NBLK, 256, 0, stream>>>(hA, hB, d_out, c_state,
                                         wpk, M0, M1, Beff,
                                         obs, flag, bar);
}

// Round 14
// 772.570 us; speedup vs baseline: 3.5118x; 3.5118x over previous
//
#include <hip/hip_runtime.h>

#define B_SZ 2048
#define HID  1024
#define G4   4096
#define IN_D 512
#define T_LEN 20
#define NT   (HID/32)

// Tile swizzle: 16B chunk q of row r stored at q ^ ((r>>1)&3) -> b128 frag
// reads land 8 banks x 2-way (free, m136); DMA writes stay linear.
#define POFF(r, q) ((r)*32 + ((((q) ^ (((r) >> 1) & 3))) << 3))

typedef __attribute__((ext_vector_type(8))) _Float16 f16x8;
typedef __attribute__((ext_vector_type(4))) float f32x4;
typedef const __attribute__((address_space(1))) void* gas_p;
typedef __attribute__((address_space(3))) void* las_p;

__device__ __forceinline__ float bf2f(ushort u){
  union { unsigned int i; float f; } v; v.i = ((unsigned int)u) << 16; return v.f;
}
__device__ __forceinline__ ushort f2bf(float f){
  union { float f; unsigned int i; } v; v.f = f;
  unsigned int r = v.i + 0x7fffu + ((v.i >> 16) & 1u);
  return (ushort)(r >> 16);
}
// fp16 RTN. All tensor magnitudes here (|h|<=1, |W|~0.03, |c0|~N(0,1)) are far
// inside fp16 range; rel err 2^-11 beats bf16's 2^-9.
__device__ __forceinline__ ushort f2h(float f){
  _Float16 h = (_Float16)f;
  union { _Float16 h; ushort u; } v; v.h = h; return v.u;
}
__device__ __forceinline__ float rdv(const void* p, long idx, int fl){
  return fl ? ((const float*)p)[idx] : bf2f(((const ushort*)p)[idx]);
}
__device__ __forceinline__ float sigm(float x){ return 1.0f/(1.0f + __expf(-x)); }
__device__ __forceinline__ float tanh_f(float x){
  float e = __expf(2.0f*x);
  return 1.0f - 2.0f/(e + 1.0f);
}

// flag=1 -> fp32 inputs; flag=0 -> bf16.
__global__ void detect_dtype(const ushort* __restrict__ h0bits, int* __restrict__ flag){
  int weird = 0;
  for (int i = 0; i < 256; i += 2){
    float a = fabsf(bf2f(h0bits[i]));
    if (!(a >= 1e-8f && a <= 1e4f)) weird++;
  }
  *flag = (weird >= 32) ? 1 : 0;
}

// Packed+swizzled fp16 layouts (every wave-level access = dense span):
//   h: tile (mb*32+kt) of 4096 halfs, element (b&127, j&31) at POFF
//   W: tile (nb*32+kt) of 4096 halfs, row r = g*32+(j&31)
__global__ void canon(const void* __restrict__ h0, const void* __restrict__ c0,
                      const void* __restrict__ whh, const int* __restrict__ flag,
                      ushort* __restrict__ hA,
                      float* __restrict__ c_state,
                      ushort* __restrict__ wpk){
  const int fl = *flag;
  long i = (long)blockIdx.x * 256 + threadIdx.x;
  const long N1 = (long)B_SZ * HID;
  const long N3 = (long)G4 * HID;
  if (i < N1){
    const int b = (int)(i >> 10), j = (int)(i & 1023);
    const int r = b & 127, q = (j >> 3) & 3;
    const long po = ((long)(b >> 7)*32 + (j >> 5))*4096 + POFF(r, q) + (j & 7);
    hA[po] = f2h(rdv(h0, i, fl));
    return;
  }
  i -= N1;
  if (i < N1){ c_state[i] = rdv(c0, i, fl); return; }
  i -= N1;
  if (i < N3){
    const int n = (int)(i >> 10), k = (int)(i & 1023);
    const int g = n >> 10, j = n & 1023;
    const int nb = j >> 5, r = g*32 + (j & 31);
    const int kt = k >> 5, q = (k >> 3) & 3;
    const long base = ((long)(nb*32 + kt))*4096 + POFF(r, q) + (k & 7);
    wpk[base] = f2h(rdv(whh, i, fl));
  }
}

// Fold embedding + input GEMM + biases into exact rank-2 update:
// gates_x[t,b,n] = obs[t,b,0]*M0[n] + obs[t,b,1]*M1[n] + Beff[n]
__global__ void fold_emb(const void* __restrict__ Wih, const void* __restrict__ Wemb,
                         const void* __restrict__ bemb, const void* __restrict__ bih,
                         const void* __restrict__ bhh, const int* __restrict__ flag,
                         float* __restrict__ M0, float* __restrict__ M1, float* __restrict__ Beff){
  const int n = blockIdx.x;
  const int lane = threadIdx.x;
  const int fl = *flag;
  float s0 = 0.f, s1 = 0.f, sb = 0.f;
  for (int j = lane; j < IN_D; j += 64){
    float w  = rdv(Wih, (long)n*IN_D + j, fl);
    float e0 = rdv(Wemb, 2L*j, fl);
    float e1 = rdv(Wemb, 2L*j + 1, fl);
    float be = rdv(bemb, j, fl);
    s0 += w*e0; s1 += w*e1; sb += w*be;
  }
  #pragma unroll
  for (int off = 32; off > 0; off >>= 1){
    s0 += __shfl_down(s0, off, 64);
    s1 += __shfl_down(s1, off, 64);
    sb += __shfl_down(sb, off, 64);
  }
  if (lane == 0){
    M0[n] = s0; M1[n] = s1;
    Beff[n] = sb + rdv(bih, n, fl) + rdv(bhh, n, fl);
  }
}

// BARRIER-FREE GEMM: each wave is a self-contained pipeline. Wave (wm,wn)
// DMAs its OWN A row-half (4KB) and B col-half (4KB) into WAVE-PRIVATE LDS
// double-buffers and fences only on its own vmcnt. Zero s_barrier /
// __syncthreads in the kernel -> no convoy: the R0-R12 ledger showed a 2x gap
// between the 2300cyc/iter wall and the 1170cyc resource floor that was
// invariant to occupancy/traffic/barrier-count/prefetch-depth -- the coupled
// block barrier was the one untested invariant. Operands are duplicated 2x
// across waves: LDS traffic unchanged (128 KB/CU/iter), L2 traffic 2x
// (64 KB/CU/iter ~ 76% of per-XCD L2 BW, feasible). Overwrite hazard (DMA
// into the buffer just read) fenced by lgkmcnt(0)+sched_barrier before the
// DMA issue; frag data is in VGPRs by then. Same MFMA order as R4/R11 ->
// bit-identical output.
__global__ __launch_bounds__(256, 2)
void lstm_step(const ushort* __restrict__ hin, ushort* __restrict__ hout,
               void* __restrict__ out_final,
               float* __restrict__ c_state,
               const ushort* __restrict__ wpk,
               const float* __restrict__ M0, const float* __restrict__ M1,
               const float* __restrict__ Beff,
               const void* __restrict__ obs_raw, int t_step,
               const int* __restrict__ flag, int is_final)
{
  // wave w, buf b at (w*2+b)*4096 halfs; per buf: [A 2048 | B 2048]; 64 KB.
  __shared__ __align__(16) ushort lds[8*4096];

  const int tid  = threadIdx.x;
  const int wave = tid >> 6;
  const int lane = tid & 63;
  const int l15  = lane & 15;
  const int quad = lane >> 4;
  const int wm   = wave & 1;    // M half (64 rows)
  const int wn   = wave >> 1;   // j half (16 cols of each gate)

  // XCD partition: xcd x owns mb in {(x&1)*8 + 0..7}, nb in {(x>>1)*8 + 0..7}
  // -> per-XCD L2 working set = A 2MB + W 2MB (R4-proven: FETCH stays ideal).
  const int bid = blockIdx.x;
  const int xcd = bid & 7, u = bid >> 3;
  const int mb  = ((xcd & 1) << 3) | (u & 7);       // 0..15
  const int nb  = ((xcd >> 1) << 3) | (u >> 3);     // 0..31
  const int n0  = nb << 5;

  f32x4 acc[4][4];   // [gate][mt]
  #pragma unroll
  for (int g = 0; g < 4; g++)
    #pragma unroll
    for (int mt = 0; mt < 4; mt++)
      acc[g][mt] = (f32x4){0.f, 0.f, 0.f, 0.f};

  // Wave-specific global bases: A = this wave's 64-row half of the mb tile
  // (contiguous 2048 halfs per kt-tile); B = this wave's wn-16-row slice of
  // each gate group (4 chunks of 512 halfs at g*1024).
  const ushort* aB = hin + (size_t)mb*32*4096 + (size_t)wm*2048;
  const ushort* wB = wpk + (size_t)nb*32*4096 + (size_t)wn*512;

  ushort* wbase = &lds[wave * 8192];       // this wave's two 4096-half buffers
  const int lOff = lane * 8;               // 16B per lane

  // 8 vmcnt-counted instructions per tile stage (vmcnt(8) math relies on it).
  #define DMA_TILE(kt, bsel) do {                                             \
    const ushort* sa = aB + (size_t)(kt)*4096;                                \
    const ushort* sw = wB + (size_t)(kt)*4096;                                \
    ushort* d = wbase + (bsel)*4096;                                          \
    __builtin_amdgcn_global_load_lds((gas_p)(sa + 0*512  + lOff), (las_p)(d + 0*512  + lOff), 16,0,0); \
    __builtin_amdgcn_global_load_lds((gas_p)(sa + 1*512  + lOff), (las_p)(d + 1*512  + lOff), 16,0,0); \
    __builtin_amdgcn_global_load_lds((gas_p)(sa + 2*512  + lOff), (las_p)(d + 2*512  + lOff), 16,0,0); \
    __builtin_amdgcn_global_load_lds((gas_p)(sa + 3*512  + lOff), (las_p)(d + 3*512  + lOff), 16,0,0); \
    __builtin_amdgcn_global_load_lds((gas_p)(sw + 0*1024 + lOff), (las_p)(d + 2048 + 0*512 + lOff), 16,0,0); \
    __builtin_amdgcn_global_load_lds((gas_p)(sw + 1*1024 + lOff), (las_p)(d + 2048 + 1*512 + lOff), 16,0,0); \
    __builtin_amdgcn_global_load_lds((gas_p)(sw + 2*1024 + lOff), (las_p)(d + 2048 + 2*512 + lOff), 16,0,0); \
    __builtin_amdgcn_global_load_lds((gas_p)(sw + 3*1024 + lOff), (las_p)(d + 2048 + 3*512 + lOff), 16,0,0); \
  } while (0)

  // Wave-local frag-read offsets (halfs). A: local row r' = mt*16+l15 of the
  // wave's 64-row half; swizzle bits (r>>1)&3 are invariant to the wm*64 base
  // (wm*32 = 0 mod 4), so POFF(r',quad) matches the staged layout. B: chunk g
  // holds rows wn*16..+15 of gate g in source (packed) order.
  int offA[4], offB[4];
  #pragma unroll
  for (int mt = 0; mt < 4; mt++) {
    const int rp = mt*16 + l15;            // 0..63
    offA[mt] = POFF(rp, quad);             // < 2048
  }
  #pragma unroll
  for (int g = 0; g < 4; g++) {
    const int sw_ = ((wn*16 + l15) >> 1) & 3;
    offB[g] = 2048 + g*512 + l15*32 + ((quad ^ sw_) << 3);
  }

  // Prologue: this wave stages tiles 0,1 into its two buffers (16 loads).
  DMA_TILE(0, 0);
  DMA_TILE(1, 1);

  #pragma unroll 1
  for (int kt = 0; kt < NT; kt++) {
    // Own-wave fence: tile kt's 8 loads are the oldest outstanding; tile
    // kt+1's 8 stay in flight (no full drain until the tail).
    if (kt + 1 < NT) asm volatile("s_waitcnt vmcnt(8)" ::: "memory");
    else             asm volatile("s_waitcnt vmcnt(0)" ::: "memory");

    const int sb = (kt & 1) * 4096;
    f16x8 a[4], b[4];
    #pragma unroll
    for (int mt = 0; mt < 4; mt++)
      a[mt] = *reinterpret_cast<const f16x8*>(&wbase[sb + offA[mt]]);
    #pragma unroll
    for (int g = 0; g < 4; g++)
      b[g] = *reinterpret_cast<const f16x8*>(&wbase[sb + offB[g]]);

    // Frag data now requested; drain LDS returns before overwriting this
    // buffer with tile kt+2 (rule #18: sched_barrier pins the order).
    asm volatile("s_waitcnt lgkmcnt(0)" ::: "memory");
    __builtin_amdgcn_sched_barrier(0);
    if (kt + 2 < NT) DMA_TILE(kt + 2, kt & 1);

    #pragma unroll
    for (int g = 0; g < 4; g++)
      #pragma unroll
      for (int mt = 0; mt < 4; mt++)
        acc[g][mt] = __builtin_amdgcn_mfma_f32_16x16x32_f16(a[mt], b[g], acc[g][mt], 0, 0, 0);
  }
  #undef DMA_TILE

  // Epilogue: fused LSTM cell. C/D layout: col = lane&15, row = quad*4 + reg.
  const int fl = *flag;
  const int j = n0 + wn*16 + l15;
  float bi[4], m0v[4], m1v[4];
  #pragma unroll
  for (int g = 0; g < 4; g++) {
    bi[g]  = Beff[g*HID + j];
    m0v[g] = M0[g*HID + j];
    m1v[g] = M1[g*HID + j];
  }
  const int jq = (j >> 3) & 3;   // k-chunk of col j in next step's packed h
  #pragma unroll
  for (int mt = 0; mt < 4; mt++) {
    #pragma unroll
    for (int r = 0; r < 4; r++) {
      const int bl7 = wm*64 + mt*16 + quad*4 + r;   // b & 127
      const int b   = mb*128 + bl7;
      const long oidx = ((long)t_step * B_SZ + b) * 2;
      const float o0 = rdv(obs_raw, oidx, fl);
      const float o1 = rdv(obs_raw, oidx + 1, fl);
      const size_t off = (size_t)b*HID + j;
      float pi = acc[0][mt][r] + o0*m0v[0] + o1*m1v[0] + bi[0];
      float pf = acc[1][mt][r] + o0*m0v[1] + o1*m1v[1] + bi[1];
      float pg = acc[2][mt][r] + o0*m0v[2] + o1*m1v[2] + bi[2];
      float po = acc[3][mt][r] + o0*m0v[3] + o1*m1v[3] + bi[3];
      float cn = sigm(pf)*c_state[off] + sigm(pi)*tanh_f(pg);
      float hn = sigm(po)*tanh_f(cn);
      c_state[off] = cn;
      if (is_final) {
        if (fl) ((float*)out_final)[off] = hn;
        else    ((ushort*)out_final)[off] = f2bf(hn);
      } else {
        const long hpo = ((long)mb*32 + (j >> 5))*4096 + POFF(bl7, jq) + (j & 7);
        hout[hpo] = f2h(hn);
      }
    }
  }
}

extern "C" void kernel_launch(void* const* d_in, const int* in_sizes, int n_in,
                              void* d_out, int out_size, void* d_ws, size_t ws_size,
                              hipStream_t stream) {
  const void* obs  = d_in[0];
  const void* h0   = d_in[1];
  const void* c0   = d_in[2];
  const void* Wemb = d_in[3];
  const void* bemb = d_in[4];
  const void* Wih  = d_in[5];
  const void* Whh  = d_in[6];
  const void* bih  = d_in[7];
  const void* bhh  = d_in[8];

  char* w = (char*)d_ws;
  int*    flag    = (int*)w;
  float*  M0      = (float*)(w + 256);
  float*  M1      = M0 + G4;
  float*  Beff    = M1 + G4;
  float*  c_state = Beff + G4;                              // 8 MB
  ushort* wpk     = (ushort*)(c_state + (size_t)B_SZ*HID);  // 8 MB packed W (fp16)
  ushort* hA      = wpk + (size_t)G4*HID;                   // 4 MB
  ushort* hB      = hA + (size_t)B_SZ*HID;                  // 4 MB  (~24 MB total)

  detect_dtype<<<1, 1, 0, stream>>>((const ushort*)h0, flag);

  long totalCanon = 2L*B_SZ*HID + (long)G4*HID;
  canon<<<(int)((totalCanon + 255)/256), 256, 0, stream>>>(
      h0, c0, Whh, flag, hA, c_state, wpk);

  fold_emb<<<G4, 64, 0, stream>>>(Wih, Wemb, bemb, bih, bhh, flag, M0, M1, Beff);

  for (int t = 0; t < T_LEN; t++) {
    const ushort* ih = (t & 1) ? hB : hA;
    ushort* oh = (t & 1) ? hA : hB;
    lstm_step<<<512, 256, 0, stream>>>(ih, oh, d_out, c_state,
                                       wpk, M0, M1, Beff,
                                       obs, t, flag, (t == T_LEN - 1) ? 1 : 0);
  }
}

// Round 15
// 584.899 us; speedup vs baseline: 4.6386x; 1.3209x over previous
//
#include <hip/hip_runtime.h>

#define B_SZ 2048
#define HID  1024
#define G4   4096
#define IN_D 512
#define T_LEN 20
#define NT   (HID/32)

// Tile swizzle: 16B chunk q of row r stored at q ^ ((r>>1)&3) -> b128 frag
// reads land 8 banks x 2-way (free, m136); DMA writes stay linear.
#define POFF(r, q) ((r)*32 + ((((q) ^ (((r) >> 1) & 3))) << 3))

typedef __attribute__((ext_vector_type(8))) _Float16 f16x8;
typedef __attribute__((ext_vector_type(4))) float f32x4;
typedef const __attribute__((address_space(1))) void* gas_p;
typedef __attribute__((address_space(3))) void* las_p;

__device__ __forceinline__ float bf2f(ushort u){
  union { unsigned int i; float f; } v; v.i = ((unsigned int)u) << 16; return v.f;
}
__device__ __forceinline__ ushort f2bf(float f){
  union { float f; unsigned int i; } v; v.f = f;
  unsigned int r = v.i + 0x7fffu + ((v.i >> 16) & 1u);
  return (ushort)(r >> 16);
}
// fp16 RTN. All tensor magnitudes here (|h|<=1, |W|~0.03, |c0|~N(0,1)) are far
// inside fp16 range; rel err 2^-11 beats bf16's 2^-9.
__device__ __forceinline__ ushort f2h(float f){
  _Float16 h = (_Float16)f;
  union { _Float16 h; ushort u; } v; v.h = h; return v.u;
}
__device__ __forceinline__ float rdv(const void* p, long idx, int fl){
  return fl ? ((const float*)p)[idx] : bf2f(((const ushort*)p)[idx]);
}
__device__ __forceinline__ float sigm(float x){ return 1.0f/(1.0f + __expf(-x)); }
__device__ __forceinline__ float tanh_f(float x){
  float e = __expf(2.0f*x);
  return 1.0f - 2.0f/(e + 1.0f);
}

// flag=1 -> fp32 inputs; flag=0 -> bf16.
__global__ void detect_dtype(const ushort* __restrict__ h0bits, int* __restrict__ flag){
  int weird = 0;
  for (int i = 0; i < 256; i += 2){
    float a = fabsf(bf2f(h0bits[i]));
    if (!(a >= 1e-8f && a <= 1e4f)) weird++;
  }
  *flag = (weird >= 32) ? 1 : 0;
}

// Packed+swizzled fp16 layouts (every wave-level access = dense span):
//   h: tile (mb*32+kt) of 4096 halfs, element (b&127, j&31) at POFF
//   W: tile (nb*32+kt) of 4096 halfs, row r = g*32+(j&31)
__global__ void canon(const void* __restrict__ h0, const void* __restrict__ c0,
                      const void* __restrict__ whh, const int* __restrict__ flag,
                      ushort* __restrict__ hA,
                      float* __restrict__ c_state,
                      ushort* __restrict__ wpk){
  const int fl = *flag;
  long i = (long)blockIdx.x * 256 + threadIdx.x;
  const long N1 = (long)B_SZ * HID;
  const long N3 = (long)G4 * HID;
  if (i < N1){
    const int b = (int)(i >> 10), j = (int)(i & 1023);
    const int r = b & 127, q = (j >> 3) & 3;
    const long po = ((long)(b >> 7)*32 + (j >> 5))*4096 + POFF(r, q) + (j & 7);
    hA[po] = f2h(rdv(h0, i, fl));
    return;
  }
  i -= N1;
  if (i < N1){ c_state[i] = rdv(c0, i, fl); return; }
  i -= N1;
  if (i < N3){
    const int n = (int)(i >> 10), k = (int)(i & 1023);
    const int g = n >> 10, j = n & 1023;
    const int nb = j >> 5, r = g*32 + (j & 31);
    const int kt = k >> 5, q = (k >> 3) & 3;
    const long base = ((long)(nb*32 + kt))*4096 + POFF(r, q) + (k & 7);
    wpk[base] = f2h(rdv(whh, i, fl));
  }
}

// Fold embedding + input GEMM + biases into exact rank-2 update:
// gates_x[t,b,n] = obs[t,b,0]*M0[n] + obs[t,b,1]*M1[n] + Beff[n]
__global__ void fold_emb(const void* __restrict__ Wih, const void* __restrict__ Wemb,
                         const void* __restrict__ bemb, const void* __restrict__ bih,
                         const void* __restrict__ bhh, const int* __restrict__ flag,
                         float* __restrict__ M0, float* __restrict__ M1, float* __restrict__ Beff){
  const int n = blockIdx.x;
  const int lane = threadIdx.x;
  const int fl = *flag;
  float s0 = 0.f, s1 = 0.f, sb = 0.f;
  for (int j = lane; j < IN_D; j += 64){
    float w  = rdv(Wih, (long)n*IN_D + j, fl);
    float e0 = rdv(Wemb, 2L*j, fl);
    float e1 = rdv(Wemb, 2L*j + 1, fl);
    float be = rdv(bemb, j, fl);
    s0 += w*e0; s1 += w*e1; sb += w*be;
  }
  #pragma unroll
  for (int off = 32; off > 0; off >>= 1){
    s0 += __shfl_down(s0, off, 64);
    s1 += __shfl_down(s1, off, 64);
    sb += __shfl_down(sb, off, 64);
  }
  if (lane == 0){
    M0[n] = s0; M1[n] = s1;
    Beff[n] = sb + rdv(bih, n, fl) + rdv(bhh, n, fl);
  }
}

// R11 (635us best) with prefetch depth 2 -> 3: 4-buffer ring, vmcnt(4) steady
// state (tiles kt+1,kt+2,kt+3 in flight; wait frees only kt+1's 2 loads).
// Depth was the session's only variable with a positive measured slope
// (R10->R11 depth 1->2 = +2%); this extends the same mechanism. Ring ledger:
// DMA target (cur+3)&3 = tile kt-1's buffer, freed at kt-1's barrier; tile
// kt+1 residency fenced by own vmcnt(4)+s_barrier; tail waits vmcnt(2) then
// vmcnt(0). LDS 64 KB/block, still exactly 2 blocks/CU at 512 thr.
// Numerics/layout/epilogue identical to R11 -> bit-identical output.
__global__ __launch_bounds__(512, 4)
void lstm_step(const ushort* __restrict__ hin, ushort* __restrict__ hout,
               void* __restrict__ out_final,
               float* __restrict__ c_state,
               const ushort* __restrict__ wpk,
               const float* __restrict__ M0, const float* __restrict__ M1,
               const float* __restrict__ Beff,
               const void* __restrict__ obs_raw, int t_step,
               const int* __restrict__ flag, int is_final)
{
  // 4-ring x [A 4096 | B 4096] halfs = 64 KB
  __shared__ __align__(16) ushort lds[4*8192];

  const int tid  = threadIdx.x;
  const int wave = tid >> 6;
  const int lane = tid & 63;
  const int l15  = lane & 15;
  const int quad = lane >> 4;
  const int wm   = wave & 3;    // M quarter (32 rows)
  const int wn   = wave >> 2;   // j half (16 cols of each gate)

  // XCD partition: xcd x owns mb in {(x&1)*8 + 0..7}, nb in {(x>>1)*8 + 0..7}
  // -> per-XCD L2 working set = A 2MB + W 2MB (R4-proven: FETCH stays ideal).
  const int bid = blockIdx.x;
  const int xcd = bid & 7, u = bid >> 3;
  const int mb  = ((xcd & 1) << 3) | (u & 7);       // 0..15
  const int nb  = ((xcd >> 1) << 3) | (u >> 3);     // 0..31
  const int n0  = nb << 5;

  f32x4 acc[4][2];   // [gate][mt]
  #pragma unroll
  for (int g = 0; g < 4; g++)
    #pragma unroll
    for (int mt = 0; mt < 2; mt++)
      acc[g][mt] = (f32x4){0.f, 0.f, 0.f, 0.f};

  const ushort* aB = hin + (size_t)mb*32*4096;
  const ushort* wB = wpk + (size_t)nb*32*4096;

  const int dOff = tid*8;   // halfs; 512 thr x 16B = full 8KB tile per instr

  // 2 vmcnt-counted instructions per tile stage (the vmcnt math relies on this).
  #define DMA_TILE(kt, buf) do {                                              \
    const ushort* s0 = aB + (size_t)(kt)*4096;                                \
    const ushort* s1 = wB + (size_t)(kt)*4096;                                \
    ushort* d = &lds[(buf)*8192];                                             \
    __builtin_amdgcn_global_load_lds((gas_p)(s0+dOff), (las_p)(d+dOff),      16,0,0); \
    __builtin_amdgcn_global_load_lds((gas_p)(s1+dOff), (las_p)(d+4096+dOff), 16,0,0); \
  } while (0)

  // kt-invariant swizzled frag-read offsets (halfs)
  int offA[2], offB[4];
  #pragma unroll
  for (int mt = 0; mt < 2; mt++) {
    const int r = wm*32 + mt*16 + l15;             // 0..127
    offA[mt] = POFF(r, quad);
  }
  #pragma unroll
  for (int g = 0; g < 4; g++) {
    const int r = g*32 + wn*16 + l15;              // 0..127
    offB[g] = 4096 + POFF(r, quad);
  }

  // Prologue: stage tiles 0,1,2; wait only tile 0's loads (4 stay in flight).
  DMA_TILE(0, 0);
  DMA_TILE(1, 1);
  DMA_TILE(2, 2);
  asm volatile("s_waitcnt vmcnt(4)" ::: "memory");
  asm volatile("s_barrier" ::: "memory");

  int cur = 0;
  #pragma unroll 1
  for (int kt = 0; kt < NT; kt++) {
    const int sb = cur * 8192;

    f16x8 a[2], b[4];
    #pragma unroll
    for (int mt = 0; mt < 2; mt++)
      a[mt] = *reinterpret_cast<const f16x8*>(&lds[sb + offA[mt]]);
    #pragma unroll
    for (int g = 0; g < 4; g++)
      b[g] = *reinterpret_cast<const f16x8*>(&lds[sb + offB[g]]);

    // Issue tile kt+3 now: needed 3 barriers from now; its L2 latency hides
    // under this iter's MFMAs and the next two iters' work.
    if (kt + 3 < NT) {
      DMA_TILE(kt + 3, (cur + 3) & 3);
    }

    #pragma unroll
    for (int g = 0; g < 4; g++) {
      acc[g][0] = __builtin_amdgcn_mfma_f32_16x16x32_f16(a[0], b[g], acc[g][0], 0, 0, 0);
      acc[g][1] = __builtin_amdgcn_mfma_f32_16x16x32_f16(a[1], b[g], acc[g][1], 0, 0, 0);
    }

    // Counted wait: free only tile kt+1's 2 loads; deeper tiles stay in
    // flight across the barrier (no full drain until the tail).
    if      (kt + 3 < NT) asm volatile("s_waitcnt vmcnt(4)" ::: "memory");
    else if (kt + 2 < NT) asm volatile("s_waitcnt vmcnt(2)" ::: "memory");
    else                  asm volatile("s_waitcnt vmcnt(0)" ::: "memory");
    asm volatile("s_barrier" ::: "memory");
    __builtin_amdgcn_sched_barrier(0);

    cur = (cur + 1) & 3;
  }
  #undef DMA_TILE

  // Epilogue: fused LSTM cell. C/D layout: col = lane&15, row = quad*4 + reg.
  const int fl = *flag;
  const int j = n0 + wn*16 + l15;
  float bi[4], m0v[4], m1v[4];
  #pragma unroll
  for (int g = 0; g < 4; g++) {
    bi[g]  = Beff[g*HID + j];
    m0v[g] = M0[g*HID + j];
    m1v[g] = M1[g*HID + j];
  }
  const int jq = (j >> 3) & 3;   // k-chunk of col j in next step's packed h
  #pragma unroll
  for (int mt = 0; mt < 2; mt++) {
    #pragma unroll
    for (int r = 0; r < 4; r++) {
      const int bl7 = wm*32 + mt*16 + quad*4 + r;   // b & 127
      const int b   = mb*128 + bl7;
      const long oidx = ((long)t_step * B_SZ + b) * 2;
      const float o0 = rdv(obs_raw, oidx, fl);
      const float o1 = rdv(obs_raw, oidx + 1, fl);
      const size_t off = (size_t)b*HID + j;
      float pi = acc[0][mt][r] + o0*m0v[0] + o1*m1v[0] + bi[0];
      float pf = acc[1][mt][r] + o0*m0v[1] + o1*m1v[1] + bi[1];
      float pg = acc[2][mt][r] + o0*m0v[2] + o1*m1v[2] + bi[2];
      float po = acc[3][mt][r] + o0*m0v[3] + o1*m1v[3] + bi[3];
      float cn = sigm(pf)*c_state[off] + sigm(pi)*tanh_f(pg);
      float hn = sigm(po)*tanh_f(cn);
      c_state[off] = cn;
      if (is_final) {
        if (fl) ((float*)out_final)[off] = hn;
        else    ((ushort*)out_final)[off] = f2bf(hn);
      } else {
        const long hpo = ((long)mb*32 + (j >> 5))*4096 + POFF(bl7, jq) + (j & 7);
        hout[hpo] = f2h(hn);
      }
    }
  }
}

extern "C" void kernel_launch(void* const* d_in, const int* in_sizes, int n_in,
                              void* d_out, int out_size, void* d_ws, size_t ws_size,
                              hipStream_t stream) {
  const void* obs  = d_in[0];
  const void* h0   = d_in[1];
  const void* c0   = d_in[2];
  const void* Wemb = d_in[3];
  const void* bemb = d_in[4];
  const void* Wih  = d_in[5];
  const void* Whh  = d_in[6];
  const void* bih  = d_in[7];
  const void* bhh  = d_in[8];

  char* w = (char*)d_ws;
  int*    flag    = (int*)w;
  float*  M0      = (float*)(w + 256);
  float*  M1      = M0 + G4;
  float*  Beff    = M1 + G4;
  float*  c_state = Beff + G4;                              // 8 MB
  ushort* wpk     = (ushort*)(c_state + (size_t)B_SZ*HID);  // 8 MB packed W (fp16)
  ushort* hA      = wpk + (size_t)G4*HID;                   // 4 MB
  ushort* hB      = hA + (size_t)B_SZ*HID;                  // 4 MB  (~24 MB total)

  detect_dtype<<<1, 1, 0, stream>>>((const ushort*)h0, flag);

  long totalCanon = 2L*B_SZ*HID + (long)G4*HID;
  canon<<<(int)((totalCanon + 255)/256), 256, 0, stream>>>(
      h0, c0, Whh, flag, hA, c_state, wpk);

  fold_emb<<<G4, 64, 0, stream>>>(Wih, Wemb, bemb, bih, bhh, flag, M0, M1, Beff);

  for (int t = 0; t < T_LEN; t++) {
    const ushort* ih = (t & 1) ? hB : hA;
    ushort* oh = (t & 1) ? hA : hB;
    lstm_step<<<512, 512, 0, stream>>>(ih, oh, d_out, c_state,
                                       wpk, M0, M1, Beff,
                                       obs, t, flag, (t == T_LEN - 1) ? 1 : 0);
  }
}